// Round 4
// baseline (201.762 us; speedup 1.0000x reference)
//
#include <hip/hip_runtime.h>
#include <hip/hip_bf16.h>

#define RAG   2048          // BS*NA
#define KP    672           // padded K (real 650): k' = i*64+h for k'<640, aug 640..649
#define QOFF  45056         // 128*16*22

typedef __attribute__((ext_vector_type(8))) short short8;
typedef __attribute__((ext_vector_type(4))) float f32x4;

__device__ inline unsigned short f2bf(float f){
    unsigned u = __float_as_uint(f);
    u += 0x7fffu + ((u >> 16) & 1u);            // RNE
    return (unsigned short)(u >> 16);
}
__device__ inline unsigned pack2(float a, float b){
    return (unsigned)f2bf(a) | ((unsigned)f2bf(b) << 16);
}

// ---------------- K1: blocks 0..2047 = per-agent Usum rows (enemy + ally);
//                     blocks 2048..2303 = weight prepack (Bte/Bta/Wgru/B2) ----------------
__global__ void __launch_bounds__(256) k_usum(
    const float* __restrict__ ef, const float* __restrict__ hew1, const float* __restrict__ heb1,
    const float* __restrict__ af, const float* __restrict__ haw1, const float* __restrict__ hab1,
    const float* __restrict__ hew2, const float* __restrict__ heb2,
    const float* __restrict__ haw2, const float* __restrict__ hab2,
    const float* __restrict__ wih, const float* __restrict__ whh, const float* __restrict__ f2w1,
    unsigned short* __restrict__ Bte, unsigned short* __restrict__ Bta,
    unsigned short* __restrict__ Wgru, unsigned short* __restrict__ B2,
    unsigned short* __restrict__ usum)
{
    int bb = blockIdx.x, tid = threadIdx.x;
    if (bb >= RAG){
        int n = bb - RAG;   // 0..255
        for (int k = tid; k < KP; k += 256){
            unsigned short ve = 0, va = 0;
            if (k < 640){
                int h = k & 63, i = k >> 6;
                ve = f2bf(hew2[h*2820 + i*256 + n]);
                va = f2bf(haw2[h*2560 + i*256 + n]);
            } else if (k < 650){
                int i = k - 640;
                ve = f2bf(heb2[i*256 + n]);
                va = f2bf(hab2[i*256 + n]);
            }
            Bte[n*KP + k] = ve;
            Bta[n*KP + k] = va;
        }
        if (tid < 128){
            int k = tid; float v;
            if (n < 128)      v = (k < 64) ? wih[n*64 + k] : whh[n*64 + k - 64];
            else if (n < 192) v = (k < 64) ? wih[n*64 + k] : 0.f;
            else              v = (k < 64) ? 0.f : whh[(n-64)*64 + k - 64];
            Wgru[n*128 + k] = f2bf(v);
        }
        if (n < 64 && tid < 64) B2[n*64 + tid] = f2bf(f2w1[tid*64 + n]);
        return;
    }
    __shared__ float s_ef[16][10], s_af[15][10];
    __shared__ float s_he[16][64], s_ha[15][64];
    int ag = bb;
    if (tid < 160) s_ef[tid/10][tid%10] = ef[ag*160 + tid];
    if (tid < 150) s_af[tid/10][tid%10] = af[ag*150 + tid];
    __syncthreads();
    for (int idx = tid; idx < 16*64; idx += 256){
        int en = idx >> 6, h = idx & 63;
        float s = heb1[h];
#pragma unroll
        for (int i = 0; i < 10; ++i) s = fmaf(s_ef[en][i], hew1[i*64 + h], s);
        s_he[en][h] = fmaxf(s, 0.f);
    }
    for (int idx = tid; idx < 15*64; idx += 256){
        int l = idx >> 6, h = idx & 63;
        float s = hab1[h];
#pragma unroll
        for (int i = 0; i < 10; ++i) s = fmaf(s_af[l][i], haw1[i*64 + h], s);
        s_ha[l][h] = fmaxf(s, 0.f);
    }
    __syncthreads();
    for (int k = tid; k < KP; k += 256){
        float ue = 0.f, ua = 0.f;
        if (k < 640){
            int i = k >> 6, h = k & 63;
#pragma unroll
            for (int en = 0; en < 16; ++en) ue = fmaf(s_he[en][h], s_ef[en][i], ue);
#pragma unroll
            for (int l = 0; l < 15; ++l) ua = fmaf(s_ha[l][h], s_af[l][i], ua);
        } else if (k < 650){
            int i = k - 640;
#pragma unroll
            for (int en = 0; en < 16; ++en) ue += s_ef[en][i];
#pragma unroll
            for (int l = 0; l < 15; ++l) ua += s_af[l][i];
        }
        usum[ag*KP + k]         = f2bf(ue);
        usum[(RAG + ag)*KP + k] = f2bf(ua);
    }
}

// ---------------- K2: MFMA GEMMs. blocks 0..479: ally rows (A generated on-the-fly,
// passing-MLP epilogue). blocks 480..511: two stacked-usum tiles each -> emb. ----------------
__global__ void __launch_bounds__(256, 2) k_gemm(
    const unsigned short* __restrict__ Bte, const unsigned short* __restrict__ Bta,
    const float* __restrict__ haw1, const float* __restrict__ hab1,
    const float* __restrict__ af, const unsigned short* __restrict__ usum,
    const float* __restrict__ pw1, const float* __restrict__ pb1,
    const float* __restrict__ pw2, const float* __restrict__ pb2,
    float* __restrict__ emb, float* __restrict__ p2)
{
    __shared__ __align__(16) char smem[46080];
    unsigned short* sB  = (unsigned short*)smem;            // [256][40] bf16
    unsigned short* sA  = (unsigned short*)(smem + 20480);  // [64][40]
    unsigned short* sW1 = (unsigned short*)(smem + 36864);  // [64][72] pw1^T

    int tid = threadIdx.x;
    int w = tid >> 6;
    int lane = tid & 63;
    int l15 = lane & 15, quad = lane >> 4;
    int bb = blockIdx.x;

    if (bb < 480){
        f32x4 acc[4][4];
#pragma unroll
        for (int a = 0; a < 4; ++a)
#pragma unroll
        for (int b = 0; b < 4; ++b) acc[a][b] = (f32x4){0.f, 0.f, 0.f, 0.f};
        int row0 = bb * 64;
        int r = tid >> 2, c = tid & 3;
#pragma unroll
        for (int p = 0; p < 16; ++p){
            int idx = tid + p*256;
            sW1[(idx & 63)*72 + (idx >> 6)] = f2bf(pw1[idx]);
        }
        float af_reg[10];
        {
            const float* ap = af + (row0 + r)*10;
#pragma unroll
            for (int i = 0; i < 10; ++i) af_reg[i] = ap[i];
        }
        // recompute ally hypernet h1 for this row, the 16 h-values this thread packs
        float h1f[16];
#pragma unroll
        for (int q = 0; q < 8; ++q){
            int h0 = c*8 + q, h1 = 32 + c*8 + q;
            float v0 = hab1[h0], v1 = hab1[h1];
#pragma unroll
            for (int i = 0; i < 10; ++i){
                v0 = fmaf(af_reg[i], haw1[i*64 + h0], v0);
                v1 = fmaf(af_reg[i], haw1[i*64 + h1], v1);
            }
            h1f[q]     = fmaxf(v0, 0.f);
            h1f[8 + q] = fmaxf(v1, 0.f);
        }
        const unsigned short* Btb = Bta + tid*KP;
#pragma unroll
        for (int i = 0; i < 10; ++i){
#pragma unroll
            for (int hb = 0; hb < 2; ++hb){
                int kt = i*64 + hb*32;
                __syncthreads();
                uint4 bq0 = *(const uint4*)&Btb[kt + 0];
                uint4 bq1 = *(const uint4*)&Btb[kt + 8];
                uint4 bq2 = *(const uint4*)&Btb[kt + 16];
                uint4 bq3 = *(const uint4*)&Btb[kt + 24];
                float avf = af_reg[i];
                uint4 pk;
                pk.x = pack2(h1f[hb*8+0]*avf, h1f[hb*8+1]*avf);
                pk.y = pack2(h1f[hb*8+2]*avf, h1f[hb*8+3]*avf);
                pk.z = pack2(h1f[hb*8+4]*avf, h1f[hb*8+5]*avf);
                pk.w = pack2(h1f[hb*8+6]*avf, h1f[hb*8+7]*avf);
                *(uint4*)&sA[r*40 + c*8] = pk;
                *(uint4*)&sB[tid*40 + 0]  = bq0;
                *(uint4*)&sB[tid*40 + 8]  = bq1;
                *(uint4*)&sB[tid*40 + 16] = bq2;
                *(uint4*)&sB[tid*40 + 24] = bq3;
                __syncthreads();
                short8 a_[4], b_[4];
#pragma unroll
                for (int mt = 0; mt < 4; ++mt) a_[mt] = *(const short8*)&sA[(mt*16 + l15)*40 + quad*8];
#pragma unroll
                for (int nt = 0; nt < 4; ++nt) b_[nt] = *(const short8*)&sB[(w*64 + nt*16 + l15)*40 + quad*8];
#pragma unroll
                for (int mt = 0; mt < 4; ++mt)
#pragma unroll
                for (int nt = 0; nt < 4; ++nt)
                    acc[mt][nt] = __builtin_amdgcn_mfma_f32_16x16x32_bf16(a_[mt], b_[nt], acc[mt][nt], 0, 0, 0);
            }
        }
        {   // tail kstep: aug rows 640..649 (A = af[i]), 650..671 zero
            int kt = 640;
            __syncthreads();
            uint4 bq0 = *(const uint4*)&Btb[kt + 0];
            uint4 bq1 = *(const uint4*)&Btb[kt + 8];
            uint4 bq2 = *(const uint4*)&Btb[kt + 16];
            uint4 bq3 = *(const uint4*)&Btb[kt + 24];
            float v0=0.f,v1=0.f,v2=0.f,v3=0.f,v4=0.f,v5=0.f,v6=0.f,v7=0.f;
            if (c == 0){ v0=af_reg[0]; v1=af_reg[1]; v2=af_reg[2]; v3=af_reg[3];
                         v4=af_reg[4]; v5=af_reg[5]; v6=af_reg[6]; v7=af_reg[7]; }
            else if (c == 1){ v0 = af_reg[8]; v1 = af_reg[9]; }
            uint4 pk;
            pk.x = pack2(v0, v1); pk.y = pack2(v2, v3);
            pk.z = pack2(v4, v5); pk.w = pack2(v6, v7);
            *(uint4*)&sA[r*40 + c*8] = pk;
            *(uint4*)&sB[tid*40 + 0]  = bq0;
            *(uint4*)&sB[tid*40 + 8]  = bq1;
            *(uint4*)&sB[tid*40 + 16] = bq2;
            *(uint4*)&sB[tid*40 + 24] = bq3;
            __syncthreads();
            short8 a_[4], b_[4];
#pragma unroll
            for (int mt = 0; mt < 4; ++mt) a_[mt] = *(const short8*)&sA[(mt*16 + l15)*40 + quad*8];
#pragma unroll
            for (int nt = 0; nt < 4; ++nt) b_[nt] = *(const short8*)&sB[(w*64 + nt*16 + l15)*40 + quad*8];
#pragma unroll
            for (int mt = 0; mt < 4; ++mt)
#pragma unroll
            for (int nt = 0; nt < 4; ++nt)
                acc[mt][nt] = __builtin_amdgcn_mfma_f32_16x16x32_bf16(a_[mt], b_[nt], acc[mt][nt], 0, 0, 0);
        }
        // ---- fused passing-MLP epilogue: wave w == head d ----
        __syncthreads();
        unsigned short* sE = (unsigned short*)(smem + w*9216); // [64][72] bf16
#pragma unroll
        for (int mt = 0; mt < 4; ++mt)
#pragma unroll
        for (int nt = 0; nt < 4; ++nt)
#pragma unroll
        for (int rg = 0; rg < 4; ++rg)
            sE[(mt*16 + quad*4 + rg)*72 + nt*16 + l15] = f2bf(acc[mt][nt][rg]);
        __syncthreads();
        f32x4 yacc[4][4];
#pragma unroll
        for (int a = 0; a < 4; ++a)
#pragma unroll
        for (int b = 0; b < 4; ++b) yacc[a][b] = (f32x4){0.f, 0.f, 0.f, 0.f};
#pragma unroll
        for (int kb = 0; kb < 2; ++kb){
            short8 ea[4], wb[4];
#pragma unroll
            for (int mt = 0; mt < 4; ++mt) ea[mt] = *(const short8*)&sE[(mt*16 + l15)*72 + kb*32 + quad*8];
#pragma unroll
            for (int ot = 0; ot < 4; ++ot) wb[ot] = *(const short8*)&sW1[(ot*16 + l15)*72 + kb*32 + quad*8];
#pragma unroll
            for (int mt = 0; mt < 4; ++mt)
#pragma unroll
            for (int ot = 0; ot < 4; ++ot)
                yacc[mt][ot] = __builtin_amdgcn_mfma_f32_16x16x32_bf16(ea[mt], wb[ot], yacc[mt][ot], 0, 0, 0);
        }
        float pb1v[4], w2r[4][3];
#pragma unroll
        for (int ot = 0; ot < 4; ++ot){
            pb1v[ot] = pb1[ot*16 + l15];
#pragma unroll
            for (int j = 0; j < 3; ++j) w2r[ot][j] = pw2[(ot*16 + l15)*3 + j];
        }
#pragma unroll
        for (int mt = 0; mt < 4; ++mt){
            float part[4][3];
#pragma unroll
            for (int rg = 0; rg < 4; ++rg)
#pragma unroll
            for (int j = 0; j < 3; ++j) part[rg][j] = 0.f;
#pragma unroll
            for (int ot = 0; ot < 4; ++ot)
#pragma unroll
            for (int rg = 0; rg < 4; ++rg){
                float yv = fmaxf(yacc[mt][ot][rg] + pb1v[ot], 0.f);
#pragma unroll
                for (int j = 0; j < 3; ++j) part[rg][j] = fmaf(yv, w2r[ot][j], part[rg][j]);
            }
#pragma unroll
            for (int off = 1; off < 16; off <<= 1)
#pragma unroll
            for (int rg = 0; rg < 4; ++rg)
#pragma unroll
            for (int j = 0; j < 3; ++j) part[rg][j] += __shfl_xor(part[rg][j], off, 64);
            if (l15 == 0){
#pragma unroll
                for (int rg = 0; rg < 4; ++rg)
#pragma unroll
                for (int j = 0; j < 3; ++j)
                    p2[(row0 + mt*16 + quad*4 + rg)*12 + w*3 + j] = part[rg][j] + pb2[j];
            }
        }
    } else {
        // ---- small GEMM: stacked usum [4096][672] @ Bt -> emb [4096][256] fp32; 2 tiles/block ----
        for (int rep = 0; rep < 2; ++rep){
            int tile = (bb - 480)*2 + rep;
            int row0 = tile * 64;
            f32x4 acc[4][4];
#pragma unroll
            for (int a = 0; a < 4; ++a)
#pragma unroll
            for (int b = 0; b < 4; ++b) acc[a][b] = (f32x4){0.f, 0.f, 0.f, 0.f};
            const unsigned short* Btb = ((row0 < RAG) ? Bte : Bta) + tid*KP;
            const unsigned short* Ab  = usum + (row0 + (tid >> 2))*KP + (tid & 3)*8;
            int r = tid >> 2, c = tid & 3;
            for (int kt = 0; kt < KP; kt += 32){
                __syncthreads();
                uint4 aq  = *(const uint4*)&Ab[kt];
                uint4 bq0 = *(const uint4*)&Btb[kt + 0];
                uint4 bq1 = *(const uint4*)&Btb[kt + 8];
                uint4 bq2 = *(const uint4*)&Btb[kt + 16];
                uint4 bq3 = *(const uint4*)&Btb[kt + 24];
                *(uint4*)&sA[r*40 + c*8] = aq;
                *(uint4*)&sB[tid*40 + 0]  = bq0;
                *(uint4*)&sB[tid*40 + 8]  = bq1;
                *(uint4*)&sB[tid*40 + 16] = bq2;
                *(uint4*)&sB[tid*40 + 24] = bq3;
                __syncthreads();
                short8 a_[4], b_[4];
#pragma unroll
                for (int mt = 0; mt < 4; ++mt) a_[mt] = *(const short8*)&sA[(mt*16 + l15)*40 + quad*8];
#pragma unroll
                for (int nt = 0; nt < 4; ++nt) b_[nt] = *(const short8*)&sB[(w*64 + nt*16 + l15)*40 + quad*8];
#pragma unroll
                for (int mt = 0; mt < 4; ++mt)
#pragma unroll
                for (int nt = 0; nt < 4; ++nt)
                    acc[mt][nt] = __builtin_amdgcn_mfma_f32_16x16x32_bf16(a_[mt], b_[nt], acc[mt][nt], 0, 0, 0);
            }
#pragma unroll
            for (int mt = 0; mt < 4; ++mt)
#pragma unroll
            for (int nt = 0; nt < 4; ++nt)
#pragma unroll
            for (int rg = 0; rg < 4; ++rg)
                emb[(row0 + mt*16 + quad*4 + rg)*256 + w*64 + nt*16 + l15] = acc[mt][nt][rg];
        }
    }
}

// ---------------- K3: merge + GRU (MFMA) + heads, 16 agents per block ----------------
__global__ void __launch_bounds__(256) k_final(
    const float* __restrict__ own, const float* __restrict__ hidden,
    const float* __restrict__ fc1w, const float* __restrict__ fc1b,
    const float* __restrict__ mergw,
    const float* __restrict__ bih, const float* __restrict__ bhh,
    const float* __restrict__ f2b1, const float* __restrict__ f2w2, const float* __restrict__ f2b2,
    const unsigned short* __restrict__ Wgru, const unsigned short* __restrict__ B2,
    const float* __restrict__ emb, const float* __restrict__ p2,
    float* __restrict__ out)
{
    __shared__ __align__(16) unsigned short sA16[16*128];   // [agent][x(64)|h(64)] bf16
    __shared__ float sHin[16*65];                           // h_in fp32 (padded)
    __shared__ float sG[256*17];                            // gate pre-acts [col][agent]
    __shared__ float sH2f[16*65];                           // h' fp32
    __shared__ __align__(16) unsigned short sH2b[16*64];    // h' bf16
    __shared__ float sY[16*68];                             // fc2 hidden

    int tid = threadIdx.x;
    int w = tid >> 6, lane = tid & 63;
    int l15 = lane & 15, quad = lane >> 4;
    int ag0 = blockIdx.x * 16;

    // phase 0: x = relu(fc1(own) + merged), stage [x|h] bf16 + h_in fp32
#pragma unroll
    for (int p = 0; p < 4; ++p){
        int idx = tid + p*256;
        int h = idx & 63, a = idx >> 6;
        int ag = ag0 + a;
        float s = fc1b[h];
        const float* ow = own + ag*30;
#pragma unroll
        for (int c = 0; c < 30; ++c) s = fmaf(ow[c], fc1w[c*64 + h], s);
        float m0 = mergw[h], m1 = mergw[64+h], m2 = mergw[128+h], m3 = mergw[192+h];
        float mx = fmaxf(fmaxf(m0, m1), fmaxf(m2, m3));
        float e0 = __expf(m0-mx), e1 = __expf(m1-mx), e2 = __expf(m2-mx), e3 = __expf(m3-mx);
        float inv = 1.f / (e0+e1+e2+e3);
        const float* een = emb + ag*256;
        const float* eal = emb + (RAG + ag)*256;
        float mg = (e0*(een[h]+eal[h]) + e1*(een[64+h]+eal[64+h]) +
                    e2*(een[128+h]+eal[128+h]) + e3*(een[192+h]+eal[192+h])) * inv;
        float x = fmaxf(s + mg, 0.f);
        float hin = hidden[ag*64 + h];
        sA16[a*128 + h]      = f2bf(x);
        sA16[a*128 + 64 + h] = f2bf(hin);
        sHin[a*65 + h] = hin;
    }
    __syncthreads();

    // phase 1: GRU gate GEMM  [16 x 128] @ [128 x 256] -> sG
    {
        f32x4 g_[4];
#pragma unroll
        for (int t = 0; t < 4; ++t) g_[t] = (f32x4){0.f,0.f,0.f,0.f};
#pragma unroll
        for (int ks = 0; ks < 4; ++ks){
            int kt = ks*32;
            short8 a8 = *(const short8*)&sA16[l15*128 + kt + quad*8];
#pragma unroll
            for (int t = 0; t < 4; ++t){
                int col = (w*4 + t)*16 + l15;
                short8 b8 = *(const short8*)&Wgru[col*128 + kt + quad*8];
                g_[t] = __builtin_amdgcn_mfma_f32_16x16x32_bf16(a8, b8, g_[t], 0, 0, 0);
            }
        }
#pragma unroll
        for (int t = 0; t < 4; ++t){
            int col = (w*4 + t)*16 + l15;
#pragma unroll
            for (int rg = 0; rg < 4; ++rg) sG[col*17 + quad*4 + rg] = g_[t][rg];
        }
    }
    __syncthreads();

    // phase 2: gate math -> h'
#pragma unroll
    for (int p = 0; p < 4; ++p){
        int idx = tid + p*256;
        int a = idx & 15, h = idx >> 4;
        float rs  = sG[h*17 + a]        + bih[h]      + bhh[h];
        float zs  = sG[(64+h)*17 + a]   + bih[64+h]   + bhh[64+h];
        float in_ = sG[(128+h)*17 + a]  + bih[128+h];
        float hn  = sG[(192+h)*17 + a]  + bhh[128+h];
        float r = 1.f / (1.f + __expf(-rs));
        float z = 1.f / (1.f + __expf(-zs));
        float n = tanhf(in_ + r*hn);
        float hv = (1.f - z)*n + z*sHin[a*65 + h];
        sH2f[a*65 + h] = hv;
        sH2b[a*64 + h] = f2bf(hv);
    }
    __syncthreads();

    // phase 3: fc2 layer-1 GEMM [16 x 64] @ [64 x 64] -> relu -> sY
    {
        f32x4 y = (f32x4){0.f,0.f,0.f,0.f};
#pragma unroll
        for (int ks = 0; ks < 2; ++ks){
            int kt = ks*32;
            short8 a8 = *(const short8*)&sH2b[l15*64 + kt + quad*8];
            short8 b8 = *(const short8*)&B2[(w*16 + l15)*64 + kt + quad*8];
            y = __builtin_amdgcn_mfma_f32_16x16x32_bf16(a8, b8, y, 0, 0, 0);
        }
        float b1v = f2b1[w*16 + l15];
#pragma unroll
        for (int rg = 0; rg < 4; ++rg)
            sY[(quad*4 + rg)*68 + w*16 + l15] = fmaxf(y[rg] + b1v, 0.f);
    }
    __syncthreads();

    // phase 4: q = y @ f2w2 + b ; passing head ; outputs
    for (int idx = tid; idx < 16*19; idx += 256){
        int a = idx / 19, j = idx - a*19;
        float s2 = f2b2[j];
        for (int c = 0; c < 64; ++c) s2 = fmaf(sY[a*68 + c], f2w2[c*19 + j], s2);
        out[(ag0 + a)*22 + ((j < 9) ? j : j + 3)] = s2;
    }
    if (tid < 48){
        int a = tid / 3, j = tid - a*3;
        float best = -1e30f;
        const float* pp = p2 + (ag0 + a)*180;
        for (int l = 0; l < 15; ++l){
            float mean = 0.25f*(pp[l*12 + j] + pp[l*12 + 3 + j] + pp[l*12 + 6 + j] + pp[l*12 + 9 + j]);
            best = fmaxf(best, mean);
        }
        out[(ag0 + a)*22 + 9 + j] = best;
    }
#pragma unroll
    for (int p = 0; p < 4; ++p){
        int idx = tid + p*256;
        int h = idx & 63, a = idx >> 6;
        out[QOFF + (ag0 + a)*64 + h] = sH2f[a*65 + h];
    }
}

extern "C" void kernel_launch(void* const* d_in, const int* in_sizes, int n_in,
                              void* d_out, int out_size, void* d_ws, size_t ws_size,
                              hipStream_t stream) {
    const float* own    = (const float*)d_in[1];
    const float* allyf  = (const float*)d_in[2];
    const float* enemyf = (const float*)d_in[3];
    const float* hidden = (const float*)d_in[4];
    const float* fc1w   = (const float*)d_in[5];
    const float* fc1b   = (const float*)d_in[6];
    const float* hew1   = (const float*)d_in[7];
    const float* heb1   = (const float*)d_in[8];
    const float* hew2   = (const float*)d_in[9];
    const float* heb2   = (const float*)d_in[10];
    const float* haw1   = (const float*)d_in[11];
    const float* hab1   = (const float*)d_in[12];
    const float* haw2   = (const float*)d_in[13];
    const float* hab2   = (const float*)d_in[14];
    const float* mergw  = (const float*)d_in[15];
    const float* wih    = (const float*)d_in[16];
    const float* whh    = (const float*)d_in[17];
    const float* bih    = (const float*)d_in[18];
    const float* bhh    = (const float*)d_in[19];
    const float* f2w1   = (const float*)d_in[20];
    const float* f2b1   = (const float*)d_in[21];
    const float* f2w2   = (const float*)d_in[22];
    const float* f2b2   = (const float*)d_in[23];
    const float* pw1    = (const float*)d_in[24];
    const float* pb1    = (const float*)d_in[25];
    const float* pw2    = (const float*)d_in[26];
    const float* pb2    = (const float*)d_in[27];
    float* out = (float*)d_out;

    char* W = (char*)d_ws;
    unsigned short* Bte  = (unsigned short*)(W + 0);         // 256*672*2   = 344064
    unsigned short* Bta  = (unsigned short*)(W + 344064);    // 344064
    unsigned short* usum = (unsigned short*)(W + 688128);    // 4096*672*2  = 5505024
    float*          emb  = (float*)(W + 6193152);            // 4096*256*4  = 4194304
    float*          p2   = (float*)(W + 10387456);           // 30720*12*4  = 1474560
    unsigned short* Wgru = (unsigned short*)(W + 11862016);  // 256*128*2   = 65536
    unsigned short* B2   = (unsigned short*)(W + 11927552);  // 64*64*2     = 8192

    k_usum<<<RAG + 256, 256, 0, stream>>>(enemyf, hew1, heb1, allyf, haw1, hab1,
                                          hew2, heb2, haw2, hab2, wih, whh, f2w1,
                                          Bte, Bta, Wgru, B2, usum);
    k_gemm<<<512, 256, 0, stream>>>(Bte, Bta, haw1, hab1, allyf, usum,
                                    pw1, pb1, pw2, pb2, emb, p2);
    k_final<<<RAG/16, 256, 0, stream>>>(own, hidden, fc1w, fc1b, mergw,
                                        bih, bhh, f2b1, f2w2, f2b2,
                                        Wgru, B2, emb, p2, out);
}